// Round 10
// baseline (183.064 us; speedup 1.0000x reference)
//
#include <hip/hip_runtime.h>

#define NN 50000
#define D 128
#define BM 16
#define SL 6250              // NN/8, dst-slice width

typedef unsigned int uint;
typedef unsigned short ushort;
typedef __attribute__((ext_vector_type(8))) short bf16x8;
typedef __attribute__((ext_vector_type(4))) float f32x4;

static __device__ __forceinline__ ushort f2bf(float f) {
    uint u = __float_as_uint(f);
    u = (u + 0x7FFFu + ((u >> 16) & 1u)) >> 16;   // RNE
    return (ushort)u;
}

// unpack-accumulate 8 bf16 (one uint4) into a[8]
#define ADD8(a, u)                                                  \
    {                                                               \
        a[0] += __uint_as_float((u).x << 16);                       \
        a[1] += __uint_as_float((u).x & 0xFFFF0000u);               \
        a[2] += __uint_as_float((u).y << 16);                       \
        a[3] += __uint_as_float((u).y & 0xFFFF0000u);               \
        a[4] += __uint_as_float((u).z << 16);                       \
        a[5] += __uint_as_float((u).z & 0xFFFF0000u);               \
        a[6] += __uint_as_float((u).w << 16);                       \
        a[7] += __uint_as_float((u).w & 0xFFFF0000u);               \
    }

// swizzled LDS address (ushort units) of 16B-chunk ch of row r
static __device__ __forceinline__ int ladr(int r, int ch) {
    return r * D + (((ch) ^ (r & 7)) << 3);
}

// ---- fused prep: [cvt 3125 | wpack 256 | sliced hist 1024] ----
__global__ __launch_bounds__(256) void k_prep(
    const float* __restrict__ x, ushort* __restrict__ xb,
    const float* __restrict__ W0, const float* __restrict__ W1,
    const float* __restrict__ W2, const float* __restrict__ W3,
    ushort* __restrict__ P,
    const int* __restrict__ dst, int* __restrict__ hist, int E)
{
    const int bid = blockIdx.x;
    if (bid < 3125) {
        const int t = bid * 256 + threadIdx.x;
        const float4* p = reinterpret_cast<const float4*>(x) + (size_t)t * 2;
        const float4 v0 = p[0], v1 = p[1];
        uint4 u;
        u.x = (uint)f2bf(v0.x) | ((uint)f2bf(v0.y) << 16);
        u.y = (uint)f2bf(v0.z) | ((uint)f2bf(v0.w) << 16);
        u.z = (uint)f2bf(v1.x) | ((uint)f2bf(v1.y) << 16);
        u.w = (uint)f2bf(v1.z) | ((uint)f2bf(v1.w) << 16);
        reinterpret_cast<uint4*>(xb)[t] = u;
    } else if (bid < 3125 + 256) {
        const int o = (bid - 3125) * 256 + threadIdx.x;      // < 65536
        const int mat = o >> 14;
        const int idx = o & 16383;
        const int kt = idx >> 12;
        const int n  = (idx >> 5) & 127;
        const int ks = idx & 31;
        const float* W = (mat == 0) ? W0 : (mat == 1) ? W1 : (mat == 2) ? W2 : W3;
        P[o] = f2bf(W[(kt * 32 + ks) * D + n]);
    } else {
        const int hb = bid - (3125 + 256);
        const int s = hb & 7;
        const int lo = s * SL, hi = lo + SL;
        const int bs = hb >> 3;
        for (int e = bs * 256 + (int)threadIdx.x; e < E; e += 128 * 256) {
            const int d = dst[e];
            if (d >= lo && d < hi) atomicAdd(&hist[d], 1);
        }
    }
}

// ---- scan phase A: per-block (512 elems) partial sums ----
__global__ __launch_bounds__(256) void k_bsum(const int* __restrict__ hist,
                                              int* __restrict__ bsum, int n) {
    const int t = threadIdx.x;
    const int i0 = blockIdx.x * 512 + t * 2;
    int s = 0;
    if (i0 < n) s += hist[i0];
    if (i0 + 1 < n) s += hist[i0 + 1];
    #pragma unroll
    for (int o = 1; o < 64; o <<= 1) s += __shfl_xor(s, o);
    __shared__ int wsum[4];
    if ((t & 63) == 0) wsum[t >> 6] = s;
    __syncthreads();
    if (t == 0) bsum[blockIdx.x] = wsum[0] + wsum[1] + wsum[2] + wsum[3];
}

// ---- merged scan phase B+C: block offset from raw bsum + local scan -> row_off, cursor ----
__global__ __launch_bounds__(256) void k_scanapply(const int* __restrict__ hist,
        const int* __restrict__ bsum, int* __restrict__ row_off,
        int* __restrict__ cursor, int n, int E, int nb) {
    const int t = threadIdx.x;
    const int lane = t & 63, w = t >> 6;
    __shared__ int red[4], wsum[4], woff[4], baseS;

    // base = sum of bsum[j] for j < blockIdx.x
    int v = (t < nb && t < blockIdx.x) ? bsum[t] : 0;
    #pragma unroll
    for (int o = 1; o < 64; o <<= 1) v += __shfl_xor(v, o);
    if (lane == 0) red[w] = v;
    __syncthreads();
    if (t == 0) baseS = red[0] + red[1] + red[2] + red[3];
    __syncthreads();
    const int base = baseS;

    const int i0 = blockIdx.x * 512 + t * 2;
    const int v0 = (i0 < n) ? hist[i0] : 0;
    const int v1 = (i0 + 1 < n) ? hist[i0 + 1] : 0;
    const int s = v0 + v1;
    int inc = s;
    #pragma unroll
    for (int o = 1; o < 64; o <<= 1) { int u = __shfl_up(inc, o); if (lane >= o) inc += u; }
    if (lane == 63) wsum[w] = inc;
    __syncthreads();
    if (t == 0) { int r = 0; for (int k = 0; k < 4; ++k) { woff[k] = r; r += wsum[k]; } }
    __syncthreads();
    const int ex = base + woff[w] + (inc - s);
    if (i0 < n)     { row_off[i0] = ex;          cursor[i0] = ex; }
    if (i0 + 1 < n) { row_off[i0 + 1] = ex + v0; cursor[i0 + 1] = ex + v0; }
    if (blockIdx.x == 0 && t == 0) row_off[n] = E;
}

// ---- sliced CSR fill ----
__global__ __launch_bounds__(256) void k_fill_s(const int* __restrict__ src,
        const int* __restrict__ dst, int* __restrict__ cursor,
        int* __restrict__ csr, int E) {
    const int s = blockIdx.x & 7;
    const int lo = s * SL, hi = lo + SL;
    const int bs = blockIdx.x >> 3;
    const int stride = (gridDim.x >> 3) * 256;
    for (int e = bs * 256 + (int)threadIdx.x; e < E; e += stride) {
        const int d = dst[e];
        const int sv = src[e];
        if (d >= lo && d < hi) {
            const int p = atomicAdd(&cursor[d], 1);
            csr[p] = sv;
        }
    }
}

// ---- fused SAGE layer: pull-mean + dual MFMA GEMM + bias + ReLU (+ L2 norm) ----
// BM=16, 512 threads = 8 waves. 32 lanes per row in the pull: two 16-lane halves
// take alternating 4-edge batches (8 loads in flight per row), combined by shfl.
template<bool NORM>
__global__ __launch_bounds__(512, 4) void k_sage(
    const ushort* __restrict__ hb,
    const int* __restrict__ csr, const int* __restrict__ row_off,
    const ushort* __restrict__ Wps, const ushort* __restrict__ Wpn,
    const float* __restrict__ bias, ushort* __restrict__ outb,
    float* __restrict__ out, int n, int E)
{
    __shared__ __align__(16) ushort hsb[BM * D];
    __shared__ __align__(16) ushort hnb[BM * D];
    __shared__ float outt[BM * 132];
    const int row0 = blockIdx.x * BM;
    const int tid = threadIdx.x;
    const int l = tid & 63;
    const int w = tid >> 6;

    // ---- stage self tile (first 256 threads; bf16, swizzled) ----
    if (tid < 256) {
        const int r = tid >> 4;
        const int ch = tid & 15;
        const int g = row0 + r;
        uint4 u = make_uint4(0u, 0u, 0u, 0u);
        if (g < n) u = *reinterpret_cast<const uint4*>(hb + (size_t)g * D + ch * 8);
        *reinterpret_cast<uint4*>(&hsb[ladr(r, ch)]) = u;
    }

    // ---- pull neighbor mean: row r = tid>>5, half = (tid>>4)&1, chunk ql = tid&15 ----
    {
        const int r = tid >> 5;
        const int half = (tid >> 4) & 1;
        const int ql = tid & 15;
        const int g = row0 + r;
        const int Em1 = E - 1;
        int beg = 0, end = 0;
        if (g < n) { beg = row_off[g]; end = row_off[g + 1]; }
        const float invd = (end > beg) ? 1.0f / (float)(end - beg) : 0.0f;
        float a[8];
        #pragma unroll
        for (int j = 0; j < 8; ++j) a[j] = 0.f;
        const size_t off = (size_t)(ql * 8);

        int i = beg + half * 4;
        if (i + 3 < end) {
            int s0 = csr[i], s1 = csr[i + 1], s2 = csr[i + 2], s3 = csr[i + 3];
            while (true) {
                const uint4 u0 = *reinterpret_cast<const uint4*>(hb + (size_t)s0 * D + off);
                const uint4 u1 = *reinterpret_cast<const uint4*>(hb + (size_t)s1 * D + off);
                const uint4 u2 = *reinterpret_cast<const uint4*>(hb + (size_t)s2 * D + off);
                const uint4 u3 = *reinterpret_cast<const uint4*>(hb + (size_t)s3 * D + off);
                i += 8;
                const bool more = (i + 3 < end);
                int t0, t1, t2, t3;
                if (more) {
                    t0 = csr[i]; t1 = csr[i + 1]; t2 = csr[i + 2]; t3 = csr[i + 3];
                } else {
                    t0 = csr[min(i + 0, Em1)]; t1 = csr[min(i + 1, Em1)];
                    t2 = csr[min(i + 2, Em1)]; t3 = csr[min(i + 3, Em1)];
                }
                ADD8(a, u0); ADD8(a, u1); ADD8(a, u2); ADD8(a, u3);
                if (!more) break;
                s0 = t0; s1 = t1; s2 = t2; s3 = t3;
            }
        }
        // tail: remaining edges of this half's last (partial) batch
        const int te = min(i + 4, end);
        for (int j = i; j < te; ++j) {
            const int s = csr[j];
            const uint4 u = *reinterpret_cast<const uint4*>(hb + (size_t)s * D + off);
            ADD8(a, u);
        }
        // combine the two halves (lane l <-> l^16)
        #pragma unroll
        for (int j = 0; j < 8; ++j) a[j] += __shfl_xor(a[j], 16);
        if (half == 0) {
            uint4 u;
            u.x = (uint)f2bf(a[0] * invd) | ((uint)f2bf(a[1] * invd) << 16);
            u.y = (uint)f2bf(a[2] * invd) | ((uint)f2bf(a[3] * invd) << 16);
            u.z = (uint)f2bf(a[4] * invd) | ((uint)f2bf(a[5] * invd) << 16);
            u.w = (uint)f2bf(a[6] * invd) | ((uint)f2bf(a[7] * invd) << 16);
            *reinterpret_cast<uint4*>(&hnb[ladr(r, ql)]) = u;
        }
    }
    __syncthreads();

    // ---- MFMA: wave w -> n-tile w (16 rows x 16 cols), K = 128 ----
    {
        const int rA = l & 15;
        const int kg = l >> 4;
        f32x4 acc = {0.f, 0.f, 0.f, 0.f};
        #pragma unroll
        for (int kt = 0; kt < 4; ++kt) {
            const int kc = kt * 4 + kg;
            const bf16x8 as = *reinterpret_cast<const bf16x8*>(&hsb[ladr(rA, kc)]);
            const bf16x8 an = *reinterpret_cast<const bf16x8*>(&hnb[ladr(rA, kc)]);
            const size_t wo = (size_t)(kt * 128 + w * 16 + rA) * 32 + kg * 8;
            const bf16x8 bs = *reinterpret_cast<const bf16x8*>(Wps + wo);
            const bf16x8 bn = *reinterpret_cast<const bf16x8*>(Wpn + wo);
            acc = __builtin_amdgcn_mfma_f32_16x16x32_bf16(as, bs, acc, 0, 0, 0);
            acc = __builtin_amdgcn_mfma_f32_16x16x32_bf16(an, bn, acc, 0, 0, 0);
        }
        const int c0 = w * 16 + rA;      // C/D col
        const float bv = bias[c0];
        #pragma unroll
        for (int i2 = 0; i2 < 4; ++i2) {
            const int rr = kg * 4 + i2;  // C/D row
            outt[rr * 132 + c0] = fmaxf(acc[i2] + bv, 0.f);
        }
    }
    __syncthreads();

    // ---- epilogue (first 256 threads): row r = tid>>4, channels (tid&15)*8..+8 ----
    if (tid < 256) {
        const int r = tid >> 4;
        const int c = (tid & 15) * 8;
        const int g = row0 + r;
        float4 v0 = *reinterpret_cast<const float4*>(&outt[r * 132 + c]);
        float4 v1 = *reinterpret_cast<const float4*>(&outt[r * 132 + c + 4]);
        if (!NORM) {
            if (g < n) {
                uint4 u;
                u.x = (uint)f2bf(v0.x) | ((uint)f2bf(v0.y) << 16);
                u.y = (uint)f2bf(v0.z) | ((uint)f2bf(v0.w) << 16);
                u.z = (uint)f2bf(v1.x) | ((uint)f2bf(v1.y) << 16);
                u.w = (uint)f2bf(v1.z) | ((uint)f2bf(v1.w) << 16);
                *reinterpret_cast<uint4*>(outb + (size_t)g * D + c) = u;
            }
        } else {
            float ssq = v0.x * v0.x + v0.y * v0.y + v0.z * v0.z + v0.w * v0.w
                      + v1.x * v1.x + v1.y * v1.y + v1.z * v1.z + v1.w * v1.w;
            #pragma unroll
            for (int o = 1; o < 16; o <<= 1) ssq += __shfl_xor(ssq, o);
            const float scale = 1.0f / fmaxf(sqrtf(ssq), 1e-12f);
            if (g < n) {
                v0.x *= scale; v0.y *= scale; v0.z *= scale; v0.w *= scale;
                v1.x *= scale; v1.y *= scale; v1.z *= scale; v1.w *= scale;
                *reinterpret_cast<float4*>(out + (size_t)g * D + c)     = v0;
                *reinterpret_cast<float4*>(out + (size_t)g * D + c + 4) = v1;
            }
        }
    }
}

extern "C" void kernel_launch(void* const* d_in, const int* in_sizes, int n_in,
                              void* d_out, int out_size, void* d_ws, size_t ws_size,
                              hipStream_t stream) {
    const float* x   = (const float*)d_in[0];
    const int*   src = (const int*)d_in[1];
    const int*   dst = (const int*)d_in[2];
    const float* Ws0 = (const float*)d_in[3];
    const float* Wn0 = (const float*)d_in[4];
    const float* b0  = (const float*)d_in[5];
    const float* Ws1 = (const float*)d_in[6];
    const float* Wn1 = (const float*)d_in[7];
    const float* b1  = (const float*)d_in[8];
    float* out = (float*)d_out;
    const int E = in_sizes[1];

    // workspace layout (~25.8 MB + ints)
    ushort* xb     = (ushort*)d_ws;                      // NN*D bf16 = 12.8 MB
    ushort* h1b    = xb + (size_t)NN * D;                // NN*D bf16 = 12.8 MB
    ushort* Wp     = h1b + (size_t)NN * D;               // 4 * 16384 bf16 = 128 KB
    int*    hist   = (int*)(Wp + 65536);                 // NN
    int*    bsum   = hist + NN;                          // 128
    int*    row_off= bsum + 128;                         // NN+1
    int*    cursor = row_off + NN + 1;                   // NN
    int*    csr    = cursor + NN;                        // E

    ushort* Wps0 = Wp;
    ushort* Wpn0 = Wp + 16384;
    ushort* Wps1 = Wp + 32768;
    ushort* Wpn1 = Wp + 49152;

    const int nb = (NN + 511) / 512;                     // 98 scan blocks

    hipMemsetAsync(hist, 0, (size_t)NN * sizeof(int), stream);
    k_prep<<<3125 + 256 + 1024, 256, 0, stream>>>(x, xb, Ws0, Wn0, Ws1, Wn1, Wp,
                                                  dst, hist, E);
    k_bsum<<<nb, 256, 0, stream>>>(hist, bsum, NN);
    k_scanapply<<<nb, 256, 0, stream>>>(hist, bsum, row_off, cursor, NN, E, nb);
    k_fill_s<<<1024, 256, 0, stream>>>(src, dst, cursor, csr, E);

    // ---- layer 1: xb -> h1b (bf16) ----
    k_sage<false><<<(NN + BM - 1) / BM, 512, 0, stream>>>(
        xb, csr, row_off, Wps0, Wpn0, b0, h1b, nullptr, NN, E);

    // ---- layer 2 + normalize: h1b -> out (fp32) ----
    k_sage<true><<<(NN + BM - 1) / BM, 512, 0, stream>>>(
        h1b, csr, row_off, Wps1, Wpn1, b1, nullptr, out, NN, E);
}